// Round 1
// baseline (234.450 us; speedup 1.0000x reference)
//
#include <hip/hip_runtime.h>
#include <math.h>

#define NFFT 64
#define NP 8
#define HID 128

// ---------------------------------------------------------------------------
// Prep kernel: build the 64x8 complex matrix A such that
//   H_hat[m] = sum_p A[m][p] * comb[p]
// A[m][p] = sum_i ( [left[i]==p] wln[i] + [right[i]==p] wrn[i] ) * G[(i-m)&63]
// G[d] = (1/64) * sum_{n<8} window[n] * exp(+2*pi*i*n*d/64)
// (ifft -> mask first 8 taps * window -> fft collapses to circular conv by G)
// ---------------------------------------------------------------------------
__global__ __launch_bounds__(64) void ce_prep_kernel(
    const int* __restrict__ pilot_pos,
    const float* __restrict__ decay_param,
    const float* __restrict__ window_logits,
    float* __restrict__ A_ws)
{
    __shared__ float win[8];
    __shared__ float Gr[64], Gi[64];
    __shared__ float wln[64], wrn[64];
    __shared__ int lefts[64];
    __shared__ int pos[8];
    int t = threadIdx.x;
    if (t < 8) {
        pos[t] = pilot_pos[t];
        win[t] = 1.0f / (1.0f + expf(-window_logits[t]));
    }
    __syncthreads();
    float decay = log1pf(expf(decay_param[0]));  // softplus

    // G[d] for d = t
    {
        float gr = 0.f, gi = 0.f;
        #pragma unroll
        for (int n = 0; n < 8; ++n) {
            float ang = 6.283185307179586f * (float)(n * t) * (1.0f / 64.0f);
            gr += win[n] * cosf(ang);
            gi += win[n] * sinf(ang);
        }
        Gr[t] = gr * (1.0f / 64.0f);
        Gi[t] = gi * (1.0f / 64.0f);
    }
    // interpolation weights for subcarrier i = t
    {
        int l = 0;
        #pragma unroll
        for (int p = 1; p < 8; ++p) if (pos[p] <= t) l = p;   // searchsorted(right)-1
        if (l > 6) l = 6;
        float x0 = (float)pos[l], x1 = (float)pos[l + 1];
        float fi = (float)t;
        float wl = expf(-decay * fabsf(fi - x0));
        float wr = expf(-decay * fabsf(x1 - fi));
        float wsum = wl + wr + 1e-12f;
        lefts[t] = l;
        wln[t] = wl / wsum;
        wrn[t] = wr / wsum;
    }
    __syncthreads();
    // A row m = t  (scratch-indexed local arrays: fine, prep is tiny)
    float ar[8], ai[8];
    for (int p = 0; p < 8; ++p) { ar[p] = 0.f; ai[p] = 0.f; }
    for (int i = 0; i < 64; ++i) {
        int d = (i - t) & 63;
        float gr = Gr[d], gi = Gi[d];
        int l = lefts[i];
        float wa = wln[i], wb = wrn[i];
        ar[l]     += wa * gr;  ai[l]     += wa * gi;
        ar[l + 1] += wb * gr;  ai[l + 1] += wb * gi;
    }
    for (int p = 0; p < 8; ++p) {
        A_ws[t * 16 + 2 * p]     = ar[p];
        A_ws[t * 16 + 2 * p + 1] = ai[p];
    }
}

// ---------------------------------------------------------------------------
// Main kernel: one thread per batch element. Weights staged in LDS
// (W2 pre-transposed so the k-reduction is a contiguous float4 stream,
// all weight reads are wave-uniform -> LDS broadcast, conflict-free).
// h[128] lives in registers with static indexing only.
// ---------------------------------------------------------------------------
__global__ __launch_bounds__(512, 2) void ce_main_kernel(
    const float* __restrict__ Y,
    const float* __restrict__ Xp,
    const int* __restrict__ pilot_pos,
    const float* __restrict__ W1, const float* __restrict__ b1,
    const float* __restrict__ W2, const float* __restrict__ b2,
    const float* __restrict__ W3, const float* __restrict__ b3,
    const float* __restrict__ est_w, const float* __restrict__ alpha,
    const float* __restrict__ A_ws,
    float* __restrict__ out, int B)
{
    __shared__ float sW1[16 * 128];    // rows 0..15 of W1 (rest multiplies zeros)
    __shared__ float sW2T[128 * 128];  // sW2T[j][k] = W2[k][j]
    __shared__ float sW3[128 * 16];    // first 16 cols of W3 (only o[:16] used)
    __shared__ float sb1[128], sb2[128], sb3[16];
    __shared__ float sA[64 * 16];
    __shared__ int spos[8];

    int t = threadIdx.x;
    for (int i = t; i < 16 * 128; i += 512) sW1[i] = W1[i];
    // write LDS stride-1 (conflict-free); global read strided but W2 is 64KB, L2-hot
    for (int i = t; i < 128 * 128; i += 512) {
        int j = i >> 7, k = i & 127;
        sW2T[i] = W2[k * 128 + j];
    }
    for (int i = t; i < 128 * 16; i += 512) {
        int j = i >> 4, c = i & 15;
        sW3[i] = W3[j * 64 + c];
    }
    if (t < 128) sb1[t] = b1[t];
    else if (t < 256) sb2[t - 128] = b2[t - 128];
    else if (t < 272) sb3[t - 256] = b3[t - 256];
    for (int i = t; i < 64 * 16; i += 512) sA[i] = A_ws[i];
    if (t < 8) spos[t] = pilot_pos[t];
    __syncthreads();

    int b = blockIdx.x * 512 + t;
    if (b >= B) return;

    float w0 = est_w[0];
    float al = fminf(fmaxf(alpha[0], 0.f), 1.f);
    float one_m_al = 1.0f - al;

    // --- inputs ---
    float xp[16];
    {
        const float4* p4 = (const float4*)(Xp + (size_t)b * 16);
        #pragma unroll
        for (int q = 0; q < 4; ++q) {
            float4 v = p4[q];
            xp[4 * q + 0] = v.x; xp[4 * q + 1] = v.y;
            xp[4 * q + 2] = v.z; xp[4 * q + 3] = v.w;
        }
    }
    float lsr[8], lsi[8];
    {
        const float* yrow = Y + (size_t)b * 128;
        #pragma unroll
        for (int p = 0; p < 8; ++p) {
            float2 y = *(const float2*)(yrow + spos[p] * 2);
            float c = xp[2 * p], d = xp[2 * p + 1];
            float inv = 1.0f / (c * c + d * d);
            lsr[p] = (y.x * c + y.y * d) * inv;
            lsi[p] = (y.y * c - y.x * d) * inv;
        }
    }

    // --- layer 1: 16 -> 128, relu ---
    float h[128];
    #pragma unroll
    for (int j4 = 0; j4 < 32; ++j4) {
        float a0 = sb1[4 * j4 + 0], a1 = sb1[4 * j4 + 1];
        float a2 = sb1[4 * j4 + 2], a3 = sb1[4 * j4 + 3];
        #pragma unroll
        for (int k = 0; k < 16; ++k) {
            float xk = (k & 1) ? lsi[k >> 1] : lsr[k >> 1];
            float4 w = *(const float4*)(sW1 + k * 128 + 4 * j4);
            a0 += xk * w.x; a1 += xk * w.y; a2 += xk * w.z; a3 += xk * w.w;
        }
        h[4 * j4 + 0] = fmaxf(a0, 0.f);
        h[4 * j4 + 1] = fmaxf(a1, 0.f);
        h[4 * j4 + 2] = fmaxf(a2, 0.f);
        h[4 * j4 + 3] = fmaxf(a3, 0.f);
    }

    // --- layers 2+3 fused: h2[j] never materialized ---
    float oacc[16];
    #pragma unroll
    for (int q = 0; q < 16; ++q) oacc[q] = sb3[q];
    for (int j = 0; j < 128; ++j) {
        float s0 = 0.f, s1 = 0.f, s2 = 0.f, s3 = 0.f;
        const float4* wrow = (const float4*)(sW2T + j * 128);
        #pragma unroll
        for (int k4 = 0; k4 < 32; ++k4) {
            float4 w = wrow[k4];
            s0 += h[4 * k4 + 0] * w.x;
            s1 += h[4 * k4 + 1] * w.y;
            s2 += h[4 * k4 + 2] * w.z;
            s3 += h[4 * k4 + 3] * w.w;
        }
        float hj = fmaxf(sb2[j] + ((s0 + s1) + (s2 + s3)), 0.f);
        const float4* w3r = (const float4*)(sW3 + j * 16);
        #pragma unroll
        for (int q4 = 0; q4 < 4; ++q4) {
            float4 w = w3r[q4];
            oacc[4 * q4 + 0] += hj * w.x;
            oacc[4 * q4 + 1] += hj * w.y;
            oacc[4 * q4 + 2] += hj * w.z;
            oacc[4 * q4 + 3] += hj * w.w;
        }
    }

    // --- combine with weighted LS ---
    float cr[8], ci[8];
    #pragma unroll
    for (int p = 0; p < 8; ++p) {
        float nr = tanhf(oacc[p]);
        float ni = tanhf(oacc[8 + p]);
        cr[p] = al * (lsr[p] * w0) + one_m_al * nr;
        ci[p] = al * (lsi[p] * w0) + one_m_al * ni;
    }

    // --- H_hat[m] = sum_p A[m][p] * comb[p], write out ---
    float* op = out + (size_t)b * 128;
    for (int m = 0; m < 64; ++m) {
        const float4* arow = (const float4*)(sA + m * 16);
        float hr = 0.f, hi = 0.f;
        #pragma unroll
        for (int p2 = 0; p2 < 4; ++p2) {
            float4 aa = arow[p2];
            int p0 = 2 * p2, p1 = 2 * p2 + 1;
            hr += cr[p0] * aa.x - ci[p0] * aa.y;
            hi += cr[p0] * aa.y + ci[p0] * aa.x;
            hr += cr[p1] * aa.z - ci[p1] * aa.w;
            hi += cr[p1] * aa.w + ci[p1] * aa.z;
        }
        float2 o2; o2.x = hr; o2.y = hi;
        *(float2*)(op + 2 * m) = o2;
    }
}

extern "C" void kernel_launch(void* const* d_in, const int* in_sizes, int n_in,
                              void* d_out, int out_size, void* d_ws, size_t ws_size,
                              hipStream_t stream) {
    const float* Y             = (const float*)d_in[0];
    const float* Xp            = (const float*)d_in[1];
    const int*   pilot_pos     = (const int*)d_in[2];
    const float* W1            = (const float*)d_in[3];
    const float* b1            = (const float*)d_in[4];
    const float* W2            = (const float*)d_in[5];
    const float* b2            = (const float*)d_in[6];
    const float* W3            = (const float*)d_in[7];
    const float* b3            = (const float*)d_in[8];
    const float* est_w         = (const float*)d_in[9];
    const float* alpha         = (const float*)d_in[10];
    const float* decay_param   = (const float*)d_in[11];
    const float* window_logits = (const float*)d_in[12];
    float* out = (float*)d_out;
    float* A_ws = (float*)d_ws;   // 1024 floats

    int B = in_sizes[0] / 128;

    hipLaunchKernelGGL(ce_prep_kernel, dim3(1), dim3(64), 0, stream,
                       pilot_pos, decay_param, window_logits, A_ws);
    int grid = (B + 511) / 512;
    hipLaunchKernelGGL(ce_main_kernel, dim3(grid), dim3(512), 0, stream,
                       Y, Xp, pilot_pos, W1, b1, W2, b2, W3, b3,
                       est_w, alpha, A_ws, out, B);
}

// Round 4
// 150.949 us; speedup vs baseline: 1.5532x; 1.5532x over previous
//
#include <hip/hip_runtime.h>
#include <math.h>

typedef __attribute__((ext_vector_type(8))) short short8v;   // 8 bf16 bits
typedef __attribute__((ext_vector_type(4))) float f32x4;     // 16x16 MFMA acc

__device__ __forceinline__ unsigned short f2bf(float x) {
    union { float f; unsigned u; } v; v.f = x;
    unsigned r = v.u + 0x7FFF + ((v.u >> 16) & 1);   // RNE
    return (unsigned short)(r >> 16);
}
__device__ __forceinline__ float bf2f(unsigned short u) {
    union { unsigned u; float f; } v; v.u = ((unsigned)u) << 16;
    return v.f;
}

// ---------------------------------------------------------------------------
// Prep (round-1 proven): A (64x8 complex f32) into d_ws (4 KB).
//   H_hat[m] = sum_p A[m][p] * comb[p]
// ---------------------------------------------------------------------------
__global__ __launch_bounds__(64) void ce_prep_kernel(
    const int* __restrict__ pilot_pos,
    const float* __restrict__ decay_param,
    const float* __restrict__ window_logits,
    float* __restrict__ A_ws)
{
    __shared__ float win[8], Gr[64], Gi[64], wln[64], wrn[64];
    __shared__ int lefts[64], pos[8];
    int t = threadIdx.x;
    if (t < 8) {
        pos[t] = pilot_pos[t];
        win[t] = 1.0f / (1.0f + expf(-window_logits[t]));
    }
    __syncthreads();
    float decay = log1pf(expf(decay_param[0]));
    {
        float gr = 0.f, gi = 0.f;
        #pragma unroll
        for (int n = 0; n < 8; ++n) {
            float ang = 6.283185307179586f * (float)(n * t) * (1.0f / 64.0f);
            gr += win[n] * cosf(ang);
            gi += win[n] * sinf(ang);
        }
        Gr[t] = gr * (1.0f / 64.0f);
        Gi[t] = gi * (1.0f / 64.0f);
        int lft = 0;
        #pragma unroll
        for (int p = 1; p < 8; ++p) if (pos[p] <= t) lft = p;
        if (lft > 6) lft = 6;
        float x0 = (float)pos[lft], x1 = (float)pos[lft + 1], fi = (float)t;
        float wl = expf(-decay * fabsf(fi - x0));
        float wr = expf(-decay * fabsf(x1 - fi));
        float ws = wl + wr + 1e-12f;
        lefts[t] = lft; wln[t] = wl / ws; wrn[t] = wr / ws;
    }
    __syncthreads();
    float ar[8], ai[8];
    for (int p = 0; p < 8; ++p) { ar[p] = 0.f; ai[p] = 0.f; }
    for (int i = 0; i < 64; ++i) {
        int d = (i - t) & 63;
        float gr = Gr[d], gi = Gi[d];
        int lft = lefts[i];
        float wa = wln[i], wb = wrn[i];
        ar[lft]     += wa * gr;  ai[lft]     += wa * gi;
        ar[lft + 1] += wb * gr;  ai[lft + 1] += wb * gi;
    }
    for (int p = 0; p < 8; ++p) {
        A_ws[t * 16 + 2 * p]     = ar[p];
        A_ws[t * 16 + 2 * p + 1] = ai[p];
    }
}

// ---------------------------------------------------------------------------
// Main: 512 thr = 8 waves, 16 elements/wave, 128 elements/block.
// L1 = VALU f32 (no MFMA, no pad trick). L2/L3 = mfma_f32_16x16x32_bf16
// with the corpus-pinned triple:
//   A: row=lane&15, 8 contiguous k per (lane>>4) group (bijection-safe)
//   B: col=lane&15, same k-map
//   C/D: col=lane&15, row=(lane>>4)*4+reg
// All LDS tiles PLAIN row-major, padded stride 136 shorts (no XOR swizzle).
// ---------------------------------------------------------------------------
__global__ __launch_bounds__(512) void ce_main(
    const float* __restrict__ Y, const float* __restrict__ Xp,
    const int* __restrict__ pilot_pos,
    const float* __restrict__ W1, const float* __restrict__ b1,
    const float* __restrict__ W2, const float* __restrict__ b2,
    const float* __restrict__ W3, const float* __restrict__ b3,
    const float* __restrict__ est_w, const float* __restrict__ alpha,
    const float* __restrict__ A_ws,
    float* __restrict__ out, int B)
{
    __shared__ unsigned short sW2[128 * 136];   // 34 KB [col][k] pad-136
    __shared__ unsigned short sH[8][16 * 136];  // 34 KB per-wave [elem][feat] pad-136
    __shared__ float sW1T[128 * 20];            // 10 KB [col][k] pad-20
    __shared__ float sLS[128 * 16];             // 8 KB
    __shared__ unsigned short sO[128 * 16];     // 4 KB
    __shared__ float sb1[128], sb2[128], sb3[16];
    __shared__ int spos[8];

    int t = threadIdx.x;
    // ---- stage W2 as [col][k], coalesced-ish reads, b128 writes ----
    for (int i = t; i < 2048; i += 512) {
        int col = i & 127, ch = i >> 7;           // ch in 0..15
        short8v v;
        #pragma unroll
        for (int e = 0; e < 8; ++e)
            v[e] = (short)f2bf(W2[(ch * 8 + e) * 128 + col]);
        *(short8v*)(sW2 + col * 136 + ch * 8) = v;
    }
    // ---- stage W1T [col][k] f32 ----
    for (int i = t; i < 2048; i += 512) {
        int col = i >> 4, k = i & 15;
        sW1T[col * 20 + k] = W1[k * 128 + col];
    }
    if (t < 128) sb1[t] = b1[t];
    else if (t < 256) sb2[t - 128] = b2[t - 128];
    else if (t < 272) sb3[t - 256] = b3[t - 256];
    else if (t < 280) spos[t - 272] = pilot_pos[t - 272];
    __syncthreads();

    const int w = t >> 6, l = t & 63;
    const int m = l & 15, kg = l >> 4;
    const int e_loc = w * 16 + m;
    long eg = (long)blockIdx.x * 128 + e_loc;
    long egc = (eg < B) ? eg : (long)(B - 1);
    unsigned short* hw = sH[w];

    // ---- LS: lanes kg<2 compute pilots [4kg,4kg+4) of element (w,m) ----
    if (kg < 2) {
        const float* yrow = Y + egc * 128;
        const float4* xr = (const float4*)(Xp + egc * 16 + kg * 8);
        float4 x0 = xr[0], x1 = xr[1];
        int p0 = kg * 4;
        float2 y0 = *(const float2*)(yrow + spos[p0 + 0] * 2);
        float2 y1 = *(const float2*)(yrow + spos[p0 + 1] * 2);
        float2 y2 = *(const float2*)(yrow + spos[p0 + 2] * 2);
        float2 y3 = *(const float2*)(yrow + spos[p0 + 3] * 2);
        float ls[8], inv;
        inv = 1.0f / (x0.x * x0.x + x0.y * x0.y);
        ls[0] = (y0.x * x0.x + y0.y * x0.y) * inv;
        ls[1] = (y0.y * x0.x - y0.x * x0.y) * inv;
        inv = 1.0f / (x0.z * x0.z + x0.w * x0.w);
        ls[2] = (y1.x * x0.z + y1.y * x0.w) * inv;
        ls[3] = (y1.y * x0.z - y1.x * x0.w) * inv;
        inv = 1.0f / (x1.x * x1.x + x1.y * x1.y);
        ls[4] = (y2.x * x1.x + y2.y * x1.y) * inv;
        ls[5] = (y2.y * x1.x - y2.x * x1.y) * inv;
        inv = 1.0f / (x1.z * x1.z + x1.w * x1.w);
        ls[6] = (y3.x * x1.z + y3.y * x1.w) * inv;
        ls[7] = (y3.y * x1.z - y3.x * x1.w) * inv;
        float4 s0 = { ls[0], ls[1], ls[2], ls[3] };
        float4 s1 = { ls[4], ls[5], ls[6], ls[7] };
        *(float4*)(sLS + e_loc * 16 + kg * 8)     = s0;
        *(float4*)(sLS + e_loc * 16 + kg * 8 + 4) = s1;
    }
    __syncthreads();

    // ---- Layer 1 (VALU f32): lane (kg,m) -> cols [kg*32, kg*32+32) ----
    {
        const float* lsp = sLS + e_loc * 16;
        float4 L0 = *(const float4*)(lsp + 0), L1v = *(const float4*)(lsp + 4);
        float4 L2v = *(const float4*)(lsp + 8), L3v = *(const float4*)(lsp + 12);
        float lsv[16] = { L0.x, L0.y, L0.z, L0.w, L1v.x, L1v.y, L1v.z, L1v.w,
                          L2v.x, L2v.y, L2v.z, L2v.w, L3v.x, L3v.y, L3v.z, L3v.w };
        #pragma unroll
        for (int c = 0; c < 32; ++c) {
            int col = kg * 32 + c;
            const float* wcol = sW1T + col * 20;
            float acc = sb1[col];
            #pragma unroll
            for (int k = 0; k < 16; ++k) acc += lsv[k] * wcol[k];
            hw[m * 136 + col] = f2bf(fmaxf(acc, 0.f));
        }
    }
    __syncthreads();

    const f32x4 z4 = {0.f, 0.f, 0.f, 0.f};

    // ---- Layer 2 (MFMA): [16x128]@[128x128], 4 K-steps of 32 ----
    f32x4 acc2[8];
    #pragma unroll
    for (int ct = 0; ct < 8; ++ct) acc2[ct] = z4;
    #pragma unroll
    for (int ks = 0; ks < 4; ++ks) {
        int ch = ks * 4 + kg;                       // k = ch*8+e
        short8v af = *(const short8v*)(hw + m * 136 + ch * 8);
        #pragma unroll
        for (int ct = 0; ct < 8; ++ct) {
            int col = ct * 16 + m;
            short8v bfr = *(const short8v*)(sW2 + col * 136 + ch * 8);
            acc2[ct] = __builtin_amdgcn_mfma_f32_16x16x32_bf16(af, bfr, acc2[ct], 0, 0, 0);
        }
    }
    __syncthreads();                                // reads done before overwrite
    #pragma unroll
    for (int ct = 0; ct < 8; ++ct) {
        int col = ct * 16 + m;
        float bias = sb2[col];
        #pragma unroll
        for (int r = 0; r < 4; ++r) {
            int row = kg * 4 + r;                   // element within wave tile
            hw[row * 136 + col] = f2bf(fmaxf(acc2[ct][r] + bias, 0.f));
        }
    }
    __syncthreads();

    // ---- Layer 3 (MFMA): [16x128]@[128x16] ----
    f32x4 acc3 = z4;
    #pragma unroll
    for (int ks = 0; ks < 4; ++ks) {
        int ch = ks * 4 + kg;
        short8v af = *(const short8v*)(hw + m * 136 + ch * 8);
        short8v bf3;
        #pragma unroll
        for (int e = 0; e < 8; ++e)
            bf3[e] = (short)f2bf(W3[(ch * 8 + e) * 64 + m]);   // col m < 16
        acc3 = __builtin_amdgcn_mfma_f32_16x16x32_bf16(af, bf3, acc3, 0, 0, 0);
    }
    #pragma unroll
    for (int r = 0; r < 4; ++r)
        sO[(w * 16 + kg * 4 + r) * 16 + m] = f2bf(acc3[r]);
    __syncthreads();

    // ---- comb: one thread per element ----
    float w0 = est_w[0];
    float al = fminf(fmaxf(alpha[0], 0.f), 1.f);
    float oma = 1.0f - al;
    if (t < 128) {
        float* lsp = sLS + t * 16;
        float4 L0 = *(float4*)(lsp + 0), L1v = *(float4*)(lsp + 4);
        float4 L2v = *(float4*)(lsp + 8), L3v = *(float4*)(lsp + 12);
        float lv[16] = { L0.x, L0.y, L0.z, L0.w, L1v.x, L1v.y, L1v.z, L1v.w,
                         L2v.x, L2v.y, L2v.z, L2v.w, L3v.x, L3v.y, L3v.z, L3v.w };
        short8v ov0 = *(const short8v*)(sO + t * 16);
        short8v ov1 = *(const short8v*)(sO + t * 16 + 8);
        float cb[16];
        #pragma unroll
        for (int p = 0; p < 8; ++p) {
            float o_r = bf2f((unsigned short)ov0[p]) + sb3[p];
            float o_i = bf2f((unsigned short)ov1[p]) + sb3[8 + p];
            cb[2 * p]     = al * (lv[2 * p] * w0)     + oma * tanhf(o_r);
            cb[2 * p + 1] = al * (lv[2 * p + 1] * w0) + oma * tanhf(o_i);
        }
        float4 c0 = { cb[0], cb[1], cb[2], cb[3] };
        float4 c1 = { cb[4], cb[5], cb[6], cb[7] };
        float4 c2 = { cb[8], cb[9], cb[10], cb[11] };
        float4 c3 = { cb[12], cb[13], cb[14], cb[15] };
        *(float4*)(lsp + 0) = c0;  *(float4*)(lsp + 4) = c1;
        *(float4*)(lsp + 8) = c2;  *(float4*)(lsp + 12) = c3;
    }
    __syncthreads();

    // ---- epilogue matvec: thread (e2=t>>2, q=t&3) -> m = q*16..q*16+15 ----
    int e2 = t >> 2, q = t & 3;
    long eg2 = (long)blockIdx.x * 128 + e2;
    if (eg2 < B) {
        const float* lsp = sLS + e2 * 16;
        float4 C0 = *(const float4*)(lsp + 0), C1 = *(const float4*)(lsp + 4);
        float4 C2 = *(const float4*)(lsp + 8), C3 = *(const float4*)(lsp + 12);
        float cr[8] = { C0.x, C0.z, C1.x, C1.z, C2.x, C2.z, C3.x, C3.z };
        float ci[8] = { C0.y, C0.w, C1.y, C1.w, C2.y, C2.w, C3.y, C3.w };
        float* orow = out + eg2 * 128 + q * 32;
        #pragma unroll
        for (int i2 = 0; i2 < 8; ++i2) {
            int m0 = q * 16 + 2 * i2;
            const float* a0 = A_ws + m0 * 16;
            float hr0 = 0.f, hi0 = 0.f, hr1 = 0.f, hi1 = 0.f;
            #pragma unroll
            for (int p2 = 0; p2 < 4; ++p2) {
                float4 aa = *(const float4*)(a0 + 4 * p2);
                float4 ab = *(const float4*)(a0 + 16 + 4 * p2);
                int p0 = 2 * p2, p1 = 2 * p2 + 1;
                hr0 += cr[p0] * aa.x - ci[p0] * aa.y;
                hi0 += cr[p0] * aa.y + ci[p0] * aa.x;
                hr0 += cr[p1] * aa.z - ci[p1] * aa.w;
                hi0 += cr[p1] * aa.w + ci[p1] * aa.z;
                hr1 += cr[p0] * ab.x - ci[p0] * ab.y;
                hi1 += cr[p0] * ab.y + ci[p0] * ab.x;
                hr1 += cr[p1] * ab.z - ci[p1] * ab.w;
                hi1 += cr[p1] * ab.w + ci[p1] * ab.z;
            }
            float4 st = { hr0, hi0, hr1, hi1 };
            *(float4*)(orow + 4 * i2) = st;
        }
    }
}

extern "C" void kernel_launch(void* const* d_in, const int* in_sizes, int n_in,
                              void* d_out, int out_size, void* d_ws, size_t ws_size,
                              hipStream_t stream) {
    const float* Y             = (const float*)d_in[0];
    const float* Xp            = (const float*)d_in[1];
    const int*   pilot_pos     = (const int*)d_in[2];
    const float* W1            = (const float*)d_in[3];
    const float* b1            = (const float*)d_in[4];
    const float* W2            = (const float*)d_in[5];
    const float* b2            = (const float*)d_in[6];
    const float* W3            = (const float*)d_in[7];
    const float* b3            = (const float*)d_in[8];
    const float* est_w         = (const float*)d_in[9];
    const float* alpha         = (const float*)d_in[10];
    const float* decay_param   = (const float*)d_in[11];
    const float* window_logits = (const float*)d_in[12];
    float* out = (float*)d_out;
    float* A_ws = (float*)d_ws;   // 4 KB (round-1 proven)

    int B = in_sizes[0] / 128;

    hipLaunchKernelGGL(ce_prep_kernel, dim3(1), dim3(64), 0, stream,
                       pilot_pos, decay_param, window_logits, A_ws);
    int grid = (B + 127) / 128;
    hipLaunchKernelGGL(ce_main, dim3(grid), dim3(512), 0, stream,
                       Y, Xp, pilot_pos, W1, b1, W2, b2, W3, b3,
                       est_w, alpha, A_ws, out, B);
}

// Round 5
// 99.352 us; speedup vs baseline: 2.3598x; 1.5193x over previous
//
#include <hip/hip_runtime.h>
#include <math.h>

typedef __attribute__((ext_vector_type(8))) short short8v;   // 8 bf16 bits
typedef __attribute__((ext_vector_type(4))) float f32x4;     // 16x16 MFMA acc

__device__ __forceinline__ unsigned short f2bf(float x) {
    union { float f; unsigned u; } v; v.f = x;
    unsigned r = v.u + 0x7FFF + ((v.u >> 16) & 1);   // RNE
    return (unsigned short)(r >> 16);
}
__device__ __forceinline__ float bf2f(unsigned short u) {
    union { unsigned u; float f; } v; v.u = ((unsigned)u) << 16;
    return v.f;
}
__device__ __forceinline__ float fast_tanh(float x) {
    // 1 - 2/(e^{2x}+1): no NaN for any finite/inf x
    float e = __expf(2.0f * x);
    return 1.0f - 2.0f / (e + 1.0f);
}

// d_ws layout (bytes):
//   [0, 4096)      A      f32  [64][16]  (complex interleaved per pilot)
//   [4096, 12288)  W1T32  bf16 [128 col][32 k]   rows k>=16 ZERO
//   [12288, 45056) W2T    bf16 [128 col][128 k]
//   [45056, 49152) W3T    bf16 [16 col][128 k]
#define WS_A    0
#define WS_W1   4096
#define WS_W2   12288
#define WS_W3   45056

// ---------------------------------------------------------------------------
// Prep: one block, 256 threads. A-build identical to round-4 (proven).
// ---------------------------------------------------------------------------
__global__ __launch_bounds__(256) void ce_prep_kernel(
    const int* __restrict__ pilot_pos,
    const float* __restrict__ decay_param,
    const float* __restrict__ window_logits,
    const float* __restrict__ W1, const float* __restrict__ W2,
    const float* __restrict__ W3,
    char* __restrict__ ws)
{
    __shared__ float win[8], Gr[64], Gi[64], wln[64], wrn[64];
    __shared__ int lefts[64], pos[8];
    int t = threadIdx.x;
    if (t < 8) {
        pos[t] = pilot_pos[t];
        win[t] = 1.0f / (1.0f + expf(-window_logits[t]));
    }
    __syncthreads();
    float decay = log1pf(expf(decay_param[0]));
    if (t < 64) {
        float gr = 0.f, gi = 0.f;
        #pragma unroll
        for (int n = 0; n < 8; ++n) {
            float ang = 6.283185307179586f * (float)(n * t) * (1.0f / 64.0f);
            gr += win[n] * cosf(ang);
            gi += win[n] * sinf(ang);
        }
        Gr[t] = gr * (1.0f / 64.0f);
        Gi[t] = gi * (1.0f / 64.0f);
        int lft = 0;
        #pragma unroll
        for (int p = 1; p < 8; ++p) if (pos[p] <= t) lft = p;
        if (lft > 6) lft = 6;
        float x0 = (float)pos[lft], x1 = (float)pos[lft + 1], fi = (float)t;
        float wl = expf(-decay * fabsf(fi - x0));
        float wr = expf(-decay * fabsf(x1 - fi));
        float wsum = wl + wr + 1e-12f;
        lefts[t] = lft; wln[t] = wl / wsum; wrn[t] = wr / wsum;
    }
    __syncthreads();
    if (t < 64) {
        float ar[8], ai[8];
        for (int p = 0; p < 8; ++p) { ar[p] = 0.f; ai[p] = 0.f; }
        for (int i = 0; i < 64; ++i) {
            int d = (i - t) & 63;
            float gr = Gr[d], gi = Gi[d];
            int lft = lefts[i];
            float wa = wln[i], wb = wrn[i];
            ar[lft]     += wa * gr;  ai[lft]     += wa * gi;
            ar[lft + 1] += wb * gr;  ai[lft + 1] += wb * gi;
        }
        float* A = (float*)(ws + WS_A);
        for (int p = 0; p < 8; ++p) {
            A[t * 16 + 2 * p]     = ar[p];
            A[t * 16 + 2 * p + 1] = ai[p];
        }
    }
    // W1T32 [col][32], k>=16 zeroed
    unsigned short* w1t = (unsigned short*)(ws + WS_W1);
    for (int i = t; i < 128 * 32; i += 256) {
        int col = i >> 5, k = i & 31;
        w1t[i] = (k < 16) ? f2bf(W1[k * 128 + col]) : (unsigned short)0;
    }
    // W2T [col][128]
    unsigned short* w2t = (unsigned short*)(ws + WS_W2);
    for (int i = t; i < 128 * 128; i += 256) {
        int col = i >> 7, k = i & 127;
        w2t[i] = f2bf(W2[k * 128 + col]);
    }
    // W3T [16][128]
    unsigned short* w3t = (unsigned short*)(ws + WS_W3);
    for (int i = t; i < 16 * 128; i += 256) {
        int col = i >> 7, k = i & 127;
        w3t[i] = f2bf(W3[k * 64 + col]);
    }
}

// ---------------------------------------------------------------------------
// Main: 256 thr = 4 waves, 16 elements/wave, 64 elements/block.
// Weights read as fragments from global bf16 tables (L1/L2-hot, no staging).
// LDS (24.6 KB -> ~6 blocks/CU):
//   sH  per-wave [16][136] bf16 (pad-136, round-4 proven)
//   sLS [64][16] f32 (ls_in, overwritten by comb)
//   sO  [64][16] bf16
// ---------------------------------------------------------------------------
__global__ __launch_bounds__(256, 4) void ce_main(
    const float* __restrict__ Y, const float* __restrict__ Xp,
    const int* __restrict__ pilot_pos,
    const float* __restrict__ b1, const float* __restrict__ b2,
    const float* __restrict__ b3,
    const float* __restrict__ est_w, const float* __restrict__ alpha,
    const char* __restrict__ ws,
    float* __restrict__ out, int B)
{
    __shared__ unsigned short sH[4][16 * 136];   // 17408 B
    __shared__ float sLS[64 * 16];               // 4096 B
    __shared__ unsigned short sO[64 * 16];       // 2048 B
    __shared__ float sb1[128], sb2[128], sb3[16];

    const unsigned short* w1t = (const unsigned short*)(ws + WS_W1);
    const unsigned short* w2t = (const unsigned short*)(ws + WS_W2);
    const unsigned short* w3t = (const unsigned short*)(ws + WS_W3);
    const float* Amat = (const float*)(ws + WS_A);

    int t = threadIdx.x;
    if (t < 128) { sb1[t] = b1[t]; sb2[t] = b2[t]; }
    if (t < 16) sb3[t] = b3[t];

    const int w = t >> 6, l = t & 63;
    const int m = l & 15, kg = l >> 4;
    const int e_loc = w * 16 + m;
    long eg = (long)blockIdx.x * 64 + e_loc;
    long egc = (eg < B) ? eg : (long)(B - 1);

    // ---- LS: lanes kg<2 compute pilots [4kg,4kg+4) of element (w,m) ----
    short8v a1 = {0, 0, 0, 0, 0, 0, 0, 0};
    if (kg < 2) {
        const float* yrow = Y + egc * 128;
        const float4* xr = (const float4*)(Xp + egc * 16 + kg * 8);
        float4 x0 = xr[0], x1 = xr[1];
        int p0 = kg * 4;
        float2 y0 = *(const float2*)(yrow + pilot_pos[p0 + 0] * 2);
        float2 y1 = *(const float2*)(yrow + pilot_pos[p0 + 1] * 2);
        float2 y2 = *(const float2*)(yrow + pilot_pos[p0 + 2] * 2);
        float2 y3 = *(const float2*)(yrow + pilot_pos[p0 + 3] * 2);
        float ls[8], inv;
        inv = 1.0f / (x0.x * x0.x + x0.y * x0.y);
        ls[0] = (y0.x * x0.x + y0.y * x0.y) * inv;
        ls[1] = (y0.y * x0.x - y0.x * x0.y) * inv;
        inv = 1.0f / (x0.z * x0.z + x0.w * x0.w);
        ls[2] = (y1.x * x0.z + y1.y * x0.w) * inv;
        ls[3] = (y1.y * x0.z - y1.x * x0.w) * inv;
        inv = 1.0f / (x1.x * x1.x + x1.y * x1.y);
        ls[4] = (y2.x * x1.x + y2.y * x1.y) * inv;
        ls[5] = (y2.y * x1.x - y2.x * x1.y) * inv;
        inv = 1.0f / (x1.z * x1.z + x1.w * x1.w);
        ls[6] = (y3.x * x1.z + y3.y * x1.w) * inv;
        ls[7] = (y3.y * x1.z - y3.x * x1.w) * inv;
        float4 s0 = { ls[0], ls[1], ls[2], ls[3] };
        float4 s1 = { ls[4], ls[5], ls[6], ls[7] };
        *(float4*)(sLS + e_loc * 16 + kg * 8)     = s0;
        *(float4*)(sLS + e_loc * 16 + kg * 8 + 4) = s1;
        #pragma unroll
        for (int e = 0; e < 8; ++e) a1[e] = (short)f2bf(ls[e]);
    }
    __syncthreads();   // sb1/sb2/sb3 + sLS visible

    const f32x4 z4 = {0.f, 0.f, 0.f, 0.f};
    unsigned short* hw = sH[w];

    // ---- Layer 1 (MFMA): A rows = elements, k>=16 zero on BOTH operands ----
    #pragma unroll
    for (int ct = 0; ct < 8; ++ct) {
        int col = ct * 16 + m;
        short8v bfr = *(const short8v*)(w1t + col * 32 + kg * 8);
        f32x4 acc = __builtin_amdgcn_mfma_f32_16x16x32_bf16(a1, bfr, z4, 0, 0, 0);
        float bias = sb1[col];
        #pragma unroll
        for (int r = 0; r < 4; ++r) {
            int row = kg * 4 + r;
            hw[row * 136 + col] = f2bf(fmaxf(acc[r] + bias, 0.f));
        }
    }
    __syncthreads();

    // ---- Layer 2 (MFMA): [16x128]@[128x128], 4 K-steps ----
    f32x4 acc2[8];
    #pragma unroll
    for (int ct = 0; ct < 8; ++ct) acc2[ct] = z4;
    #pragma unroll
    for (int ks = 0; ks < 4; ++ks) {
        int ch = ks * 4 + kg;
        short8v af = *(const short8v*)(hw + m * 136 + ch * 8);
        #pragma unroll
        for (int ct = 0; ct < 8; ++ct) {
            int col = ct * 16 + m;
            short8v bfr = *(const short8v*)(w2t + col * 128 + ch * 8);
            acc2[ct] = __builtin_amdgcn_mfma_f32_16x16x32_bf16(af, bfr, acc2[ct], 0, 0, 0);
        }
    }
    __syncthreads();
    #pragma unroll
    for (int ct = 0; ct < 8; ++ct) {
        int col = ct * 16 + m;
        float bias = sb2[col];
        #pragma unroll
        for (int r = 0; r < 4; ++r) {
            int row = kg * 4 + r;
            hw[row * 136 + col] = f2bf(fmaxf(acc2[ct][r] + bias, 0.f));
        }
    }
    __syncthreads();

    // ---- Layer 3 (MFMA): [16x128]@[128x16] ----
    f32x4 acc3 = z4;
    #pragma unroll
    for (int ks = 0; ks < 4; ++ks) {
        int ch = ks * 4 + kg;
        short8v af = *(const short8v*)(hw + m * 136 + ch * 8);
        short8v bf3 = *(const short8v*)(w3t + m * 128 + ch * 8);   // col m < 16
        acc3 = __builtin_amdgcn_mfma_f32_16x16x32_bf16(af, bf3, acc3, 0, 0, 0);
    }
    #pragma unroll
    for (int r = 0; r < 4; ++r)
        sO[(w * 16 + kg * 4 + r) * 16 + m] = f2bf(acc3[r]);
    __syncthreads();

    // ---- comb: thread t -> element t>>2, pilot pair q=t&3 (p=2q,2q+1) ----
    float w0 = est_w[0];
    float al = fminf(fmaxf(alpha[0], 0.f), 1.f);
    float oma = 1.0f - al;
    {
        int e2 = t >> 2, q = t & 3;
        float* lsp = sLS + e2 * 16 + q * 4;
        float4 lv = *(float4*)lsp;                   // r0,i0,r1,i1 of p=2q,2q+1
        const unsigned short* op = sO + e2 * 16;
        float or0 = bf2f(op[2 * q])     + sb3[2 * q];
        float or1 = bf2f(op[2 * q + 1]) + sb3[2 * q + 1];
        float oi0 = bf2f(op[8 + 2 * q]) + sb3[8 + 2 * q];
        float oi1 = bf2f(op[9 + 2 * q]) + sb3[9 + 2 * q];
        float4 cb;
        cb.x = al * (lv.x * w0) + oma * fast_tanh(or0);
        cb.y = al * (lv.y * w0) + oma * fast_tanh(oi0);
        cb.z = al * (lv.z * w0) + oma * fast_tanh(or1);
        cb.w = al * (lv.w * w0) + oma * fast_tanh(oi1);
        *(float4*)lsp = cb;
    }
    __syncthreads();

    // ---- epilogue: per instr, wave writes 1 KB contiguous (2 elems) ----
    {
        int j = l & 31, half = l >> 5;
        // lane's two A rows (m0=2j, m0+1): 32 f32, fixed per lane
        float Ar[32];
        const float4* ap = (const float4*)(Amat + j * 32);
        #pragma unroll
        for (int q4 = 0; q4 < 8; ++q4) {
            float4 v = ap[q4];
            Ar[4 * q4 + 0] = v.x; Ar[4 * q4 + 1] = v.y;
            Ar[4 * q4 + 2] = v.z; Ar[4 * q4 + 3] = v.w;
        }
        #pragma unroll
        for (int it = 0; it < 8; ++it) {
            int e2 = w * 16 + 2 * it + half;
            long gelem = (long)blockIdx.x * 64 + e2;
            const float* lsp = sLS + e2 * 16;
            float4 C0 = *(const float4*)(lsp + 0), C1 = *(const float4*)(lsp + 4);
            float4 C2 = *(const float4*)(lsp + 8), C3 = *(const float4*)(lsp + 12);
            float cr[8] = { C0.x, C0.z, C1.x, C1.z, C2.x, C2.z, C3.x, C3.z };
            float ci[8] = { C0.y, C0.w, C1.y, C1.w, C2.y, C2.w, C3.y, C3.w };
            float hr0 = 0.f, hi0 = 0.f, hr1 = 0.f, hi1 = 0.f;
            #pragma unroll
            for (int p = 0; p < 8; ++p) {
                float a0r = Ar[2 * p], a0i = Ar[2 * p + 1];
                float a1r = Ar[16 + 2 * p], a1i = Ar[17 + 2 * p];
                hr0 += cr[p] * a0r - ci[p] * a0i;
                hi0 += cr[p] * a0i + ci[p] * a0r;
                hr1 += cr[p] * a1r - ci[p] * a1i;
                hi1 += cr[p] * a1i + ci[p] * a1r;
            }
            if (gelem < B) {
                float4 st = { hr0, hi0, hr1, hi1 };
                *(float4*)(out + gelem * 128 + j * 4) = st;
            }
        }
    }
}

extern "C" void kernel_launch(void* const* d_in, const int* in_sizes, int n_in,
                              void* d_out, int out_size, void* d_ws, size_t ws_size,
                              hipStream_t stream) {
    const float* Y             = (const float*)d_in[0];
    const float* Xp            = (const float*)d_in[1];
    const int*   pilot_pos     = (const int*)d_in[2];
    const float* W1            = (const float*)d_in[3];
    const float* b1            = (const float*)d_in[4];
    const float* W2            = (const float*)d_in[5];
    const float* b2            = (const float*)d_in[6];
    const float* W3            = (const float*)d_in[7];
    const float* b3            = (const float*)d_in[8];
    const float* est_w         = (const float*)d_in[9];
    const float* alpha         = (const float*)d_in[10];
    const float* decay_param   = (const float*)d_in[11];
    const float* window_logits = (const float*)d_in[12];
    float* out = (float*)d_out;
    char* ws = (char*)d_ws;   // 49152 B used

    int B = in_sizes[0] / 128;

    hipLaunchKernelGGL(ce_prep_kernel, dim3(1), dim3(256), 0, stream,
                       pilot_pos, decay_param, window_logits, W1, W2, W3, ws);
    int grid = (B + 63) / 64;
    hipLaunchKernelGGL(ce_main, dim3(grid), dim3(256), 0, stream,
                       Y, Xp, pilot_pos, b1, b2, b3, est_w, alpha,
                       ws, out, B);
}